// Round 7
// baseline (260.265 us; speedup 1.0000x reference)
//
#include <hip/hip_runtime.h>

typedef short sh8  __attribute__((ext_vector_type(8)));   // 8 bf16 bit-patterns
typedef __bf16 bfv8 __attribute__((ext_vector_type(8)));
typedef float  fv4  __attribute__((ext_vector_type(4)));

__device__ __forceinline__ unsigned short f2bf(float x) {  // fp32 -> bf16 RNE
    unsigned u = __float_as_uint(x);
    return (unsigned short)((u + 0x7FFFu + ((u >> 16) & 1u)) >> 16);
}
__device__ __forceinline__ float bf2f(unsigned short b) {
    return __uint_as_float(((unsigned)b) << 16);
}
__device__ __forceinline__ fv4 mfma16(sh8 a, sh8 b, fv4 c) {
    return __builtin_amdgcn_mfma_f32_16x16x32_bf16(
        __builtin_bit_cast(bfv8, a), __builtin_bit_cast(bfv8, b), c, 0, 0, 0);
}

// ---------------------------------------------------------------------------
// Stage 1: per batch, G = HtH via bf16x2 MFMA, then 20 GD iters.
// x is broadcast via wave-uniform ds_read_b128 from a per-wave 256 B LDS
// buffer (HW broadcast, conflict-free): VALU does pure fma, DS pipe carries
// the broadcasts. No readlane in any hot path (VALU->SGPR->VALU wait-states
// made rounds 2/6 run at ~2.4x nominal issue cost).
//  - staging streamed 8 rows at a time (no hcol[64] array)
//  - k-halved MFMA staging: LDS = 8 KB/batch (hi+lo [64][32] bf16 planes)
//  - G transposed through the same 8 KB overlay in two 32-row halves
// 256-thread blocks = 4 independent waves, 1 batch each, no __syncthreads.
// ---------------------------------------------------------------------------
#define PB 4

__global__ __launch_bounds__(256, 3) void solve_fused(
    const float* __restrict__ y, const float* __restrict__ H,
    const float* __restrict__ x0, const float* __restrict__ step_size,
    const int* __restrict__ iters, float* __restrict__ z_out)
{
    __shared__ __align__(16) char ldsraw[PB * 8192];
    __shared__ __align__(16) float xbuf[PB * 64];   // per-wave broadcast buffer
    const int lane = threadIdx.x & 63;
    const int wv   = threadIdx.x >> 6;
    const int b    = blockIdx.x * PB + wv;

    short* hip = (short*)(ldsraw + wv * 8192);    // [64][32] hi plane (4 KB)
    short* lop = hip + 2048;                      // [64][32] lo plane (4 KB)
    float* gm  = (float*)(ldsraw + wv * 8192);    // [32][64] fp32 overlay (8 KB)
    float* xb_ = xbuf + wv * 64;

    const float* __restrict__ Hb = H + (size_t)b * 4096;
    xb_[lane] = y[(size_t)b * 64 + lane];         // y -> broadcast buffer
    const int fr = lane & 15, fg = lane >> 4;

    fv4 acc[4][4];
    #pragma unroll
    for (int mt = 0; mt < 4; ++mt)
        #pragma unroll
        for (int nt = 0; nt < 4; ++nt)
            acc[mt][nt] = fv4{0.f, 0.f, 0.f, 0.f};

    float hty0 = 0.f, hty1 = 0.f, hty2 = 0.f, hty3 = 0.f;

    #pragma unroll
    for (int kk = 0; kk < 2; ++kk) {
        // --- stream-stage 32 rows of H (k-half kk): load, Hty-fma, cvt, write
        #pragma unroll
        for (int g = 0; g < 4; ++g) {
            const int r0 = kk * 32 + g * 8;
            float hv[8];
            #pragma unroll
            for (int i = 0; i < 8; ++i)
                hv[i] = Hb[(size_t)(r0 + i) * 64 + lane];

            // y[r0..r0+7] via uniform LDS reads (broadcast, DS pipe)
            const fv4 ya = *(const fv4*)(xb_ + r0);
            const fv4 yb = *(const fv4*)(xb_ + r0 + 4);
            hty0 = fmaf(hv[0], ya[0], hty0);
            hty1 = fmaf(hv[1], ya[1], hty1);
            hty2 = fmaf(hv[2], ya[2], hty2);
            hty3 = fmaf(hv[3], ya[3], hty3);
            hty0 = fmaf(hv[4], yb[0], hty0);
            hty1 = fmaf(hv[5], yb[1], hty1);
            hty2 = fmaf(hv[6], yb[2], hty2);
            hty3 = fmaf(hv[7], yb[3], hty3);

            sh8 vhi, vlo;
            #pragma unroll
            for (int i = 0; i < 8; ++i) {
                const unsigned short hbf = f2bf(hv[i]);
                vhi[i] = (short)hbf;
                vlo[i] = (short)f2bf(hv[i] - bf2f(hbf));
            }
            // chunk swizzle: chunk g of row `lane` stored at chunk g^(lane&3)
            const int sw = (g ^ (lane & 3)) * 8;
            *(sh8*)(hip + lane * 32 + sw) = vhi;
            *(sh8*)(lop + lane * 32 + sw) = vlo;
        }

        // --- fragments for this k-half: row = 16tt+fr, k-chunk fg (swizzled)
        sh8 fh[4], fl[4];
        #pragma unroll
        for (int tt = 0; tt < 4; ++tt) {
            const int row = tt * 16 + fr;
            const int sw  = (fg ^ (row & 3)) * 8;
            fh[tt] = *(const sh8*)(hip + row * 32 + sw);
            fl[tt] = *(const sh8*)(lop + row * 32 + sw);
        }

        // --- 48 MFMAs: hi*hi + hi*lo + lo*hi, fp32 accumulate
        #pragma unroll
        for (int mt = 0; mt < 4; ++mt)
            #pragma unroll
            for (int nt = 0; nt < 4; ++nt) {
                fv4 a = acc[mt][nt];
                a = mfma16(fh[mt], fh[nt], a);
                a = mfma16(fh[mt], fl[nt], a);
                a = mfma16(fl[mt], fh[nt], a);
                acc[mt][nt] = a;
            }

        // fragment reads must land before the planes are overwritten
        asm volatile("s_waitcnt lgkmcnt(0)" ::: "memory");
    }

    const float hty = (hty0 + hty1) + (hty2 + hty3);

    // --- G transpose through 8 KB overlay, two 32-row halves.
    // store: G[row][col] at gm[gr*64 + (col ^ ((fg&1)<<4))]  (32-bank spread)
    float gcol[64];
    #pragma unroll
    for (int half = 0; half < 2; ++half) {
        #pragma unroll
        for (int mh = 0; mh < 2; ++mh) {
            const int mt = half * 2 + mh;
            #pragma unroll
            for (int nt = 0; nt < 4; ++nt)
                #pragma unroll
                for (int i = 0; i < 4; ++i) {
                    const int gr  = mh * 16 + fg * 4 + i;      // local row 0..31
                    const int col = nt * 16 + fr;
                    gm[gr * 64 + (col ^ ((fg & 1) << 4))] = acc[mt][nt][i];
                }
        }
        #pragma unroll
        for (int s = 0; s < 32; ++s) {
            const int swz = ((s >> 2) & 1) << 4;
            gcol[half * 32 + s] = gm[s * 64 + (lane ^ swz)];
        }
        asm volatile("s_waitcnt lgkmcnt(0)" ::: "memory");
    }

    // --- GD loop: x broadcast via uniform ds_read_b128 (no readlane).
    // Same-wave DS in-order execution makes the write->read RAW safe.
    float xv = x0[(size_t)b * 64 + lane];
    const float ts = 2.0f * step_size[0];
    const int n_it = iters[0];

    for (int it = 0; it < n_it; ++it) {
        xb_[lane] = xv;
        float w0=0.f,w1=0.f,w2=0.f,w3=0.f,w4=0.f,w5=0.f,w6=0.f,w7=0.f;
        #pragma unroll
        for (int p = 0; p < 8; ++p) {
            const fv4 xa = *(const fv4*)(xb_ + p * 8);       // uniform -> bcast
            const fv4 xc = *(const fv4*)(xb_ + p * 8 + 4);
            w0 = fmaf(gcol[p*8+0], xa[0], w0);
            w1 = fmaf(gcol[p*8+1], xa[1], w1);
            w2 = fmaf(gcol[p*8+2], xa[2], w2);
            w3 = fmaf(gcol[p*8+3], xa[3], w3);
            w4 = fmaf(gcol[p*8+4], xc[0], w4);
            w5 = fmaf(gcol[p*8+5], xc[1], w5);
            w6 = fmaf(gcol[p*8+6], xc[2], w6);
            w7 = fmaf(gcol[p*8+7], xc[3], w7);
        }
        const float w = ((w0+w1)+(w2+w3)) + ((w4+w5)+(w6+w7));
        xv = fmaf(ts, hty - w, xv);
    }

    z_out[(size_t)b * 64 + lane] = xv;
}

// ---------------------------------------------------------------------------
// Weight transposes so per-feature weight loads coalesce (runs once, tiny).
// ---------------------------------------------------------------------------
__global__ __launch_bounds__(256) void transpose_prep(
    const float* __restrict__ Wih, const float* __restrict__ Whh,
    const float* __restrict__ wx, float* __restrict__ wt_ih,
    float* __restrict__ wt_hh, float* __restrict__ wxt)
{
    int idx = blockIdx.x*256 + threadIdx.x;
    if (idx < 64*256) {
        int k = idx >> 8, j = idx & 255;
        wt_ih[idx] = Wih[j*64 + k];
        return;
    }
    idx -= 64*256;
    if (idx < 256*256) {
        int k = idx >> 8, j = idx & 255;
        wt_hh[idx] = Whh[j*256 + k];
        return;
    }
    idx -= 256*256;
    {
        int k = idx >> 6, u = idx & 63;
        wxt[idx] = wx[u*256 + k];
    }
}

// ---------------------------------------------------------------------------
// Stage 2: h_new[b][j] = relu(z[b]·W_ih[j] + h[b]·W_hh[j] + b_ih[j] + b_hh[j])
// ---------------------------------------------------------------------------
#define BT   32
#define ASTR 324

__global__ __launch_bounds__(256) void rnn_fused(
    const float* __restrict__ z, const float* __restrict__ h,
    const float* __restrict__ wt_ih, const float* __restrict__ wt_hh,
    const float* __restrict__ b_ih, const float* __restrict__ b_hh,
    float* __restrict__ h_new)
{
    __shared__ __align__(16) float act[BT*ASTR];   // 41472 B
    const int t = threadIdx.x;
    const int b0 = blockIdx.x * BT;

    #pragma unroll
    for (int i = 0; i < 2; ++i) {          // z tile: 32 x 64
        int f = t + 256*i, b = f >> 4, c = (f & 15) * 4;
        *(fv4*)(act + b*ASTR + c) = *(const fv4*)(z + (size_t)(b0+b)*64 + c);
    }
    #pragma unroll
    for (int i = 0; i < 8; ++i) {          // h tile: 32 x 256
        int f = t + 256*i, b = f >> 6, c = (f & 63) * 4;
        *(fv4*)(act + b*ASTR + 64 + c) = *(const fv4*)(h + (size_t)(b0+b)*256 + c);
    }
    __syncthreads();

    float acc[BT];
    {
        const float bias = b_ih[t] + b_hh[t];
        #pragma unroll
        for (int b = 0; b < BT; ++b) acc[b] = bias;
    }

    float w[64];
    #pragma unroll 1
    for (int kc = 0; kc < 5; ++kc) {       // k-chunks: 0 -> z, 1..4 -> h
        if (kc == 0) {
            #pragma unroll
            for (int k = 0; k < 64; ++k) w[k] = wt_ih[k*256 + t];
        } else {
            const float* wsrc = wt_hh + (size_t)(kc-1)*64*256;
            #pragma unroll
            for (int k = 0; k < 64; ++k) w[k] = wsrc[k*256 + t];
        }
        const int abase = kc*64;
        #pragma unroll
        for (int bq = 0; bq < BT; bq += 4) {
            const float* a0 = act + (bq+0)*ASTR + abase;
            const float* a1 = act + (bq+1)*ASTR + abase;
            const float* a2 = act + (bq+2)*ASTR + abase;
            const float* a3 = act + (bq+3)*ASTR + abase;
            #pragma unroll
            for (int k4 = 0; k4 < 16; ++k4) {
                fv4 v0 = *(const fv4*)(a0 + k4*4);
                fv4 v1 = *(const fv4*)(a1 + k4*4);
                fv4 v2 = *(const fv4*)(a2 + k4*4);
                fv4 v3 = *(const fv4*)(a3 + k4*4);
                #pragma unroll
                for (int u = 0; u < 4; ++u) {
                    acc[bq+0] = fmaf(w[k4*4+u], v0[u], acc[bq+0]);
                    acc[bq+1] = fmaf(w[k4*4+u], v1[u], acc[bq+1]);
                    acc[bq+2] = fmaf(w[k4*4+u], v2[u], acc[bq+2]);
                    acc[bq+3] = fmaf(w[k4*4+u], v3[u], acc[bq+3]);
                }
            }
        }
    }

    #pragma unroll
    for (int b = 0; b < BT; ++b)
        h_new[(size_t)(b0+b)*256 + t] = fmaxf(acc[b], 0.f);
}

// ---------------------------------------------------------------------------
// Stage 3: x_out[b][u] = h_new[b]·w_x[u] + b_x[u]
// ---------------------------------------------------------------------------
#define CB 64

__global__ __launch_bounds__(256) void out_proj(
    const float* __restrict__ h_new, const float* __restrict__ wxt,
    const float* __restrict__ b_x, float* __restrict__ x_out)
{
    __shared__ __align__(16) float hl[CB*256];   // 65536 B
    const int t = threadIdx.x, lane = t & 63, wv = t >> 6;
    const int b0 = blockIdx.x * CB;

    #pragma unroll
    for (int i = 0; i < 16; ++i) {
        int f = t + 256*i, b = f >> 6, c = (f & 63) * 4;
        *(fv4*)(hl + b*256 + c) = *(const fv4*)(h_new + (size_t)(b0+b)*256 + c);
    }
    __syncthreads();

    float acc[16];
    {
        const float bx = b_x[lane];
        #pragma unroll
        for (int i = 0; i < 16; ++i) acc[i] = bx;
    }

    float wxc[64];
    #pragma unroll 1
    for (int kc = 0; kc < 4; ++kc) {
        #pragma unroll
        for (int k = 0; k < 64; ++k)
            wxc[k] = wxt[(size_t)(kc*64 + k)*64 + lane];
        const int bb = wv * 16;
        #pragma unroll
        for (int bq = 0; bq < 16; bq += 4) {
            const float* h0 = hl + (bb+bq+0)*256 + kc*64;
            const float* h1 = hl + (bb+bq+1)*256 + kc*64;
            const float* h2 = hl + (bb+bq+2)*256 + kc*64;
            const float* h3 = hl + (bb+bq+3)*256 + kc*64;
            #pragma unroll
            for (int k4 = 0; k4 < 16; ++k4) {
                fv4 v0 = *(const fv4*)(h0 + k4*4);
                fv4 v1 = *(const fv4*)(h1 + k4*4);
                fv4 v2 = *(const fv4*)(h2 + k4*4);
                fv4 v3 = *(const fv4*)(h3 + k4*4);
                #pragma unroll
                for (int u = 0; u < 4; ++u) {
                    acc[bq+0] = fmaf(wxc[k4*4+u], v0[u], acc[bq+0]);
                    acc[bq+1] = fmaf(wxc[k4*4+u], v1[u], acc[bq+1]);
                    acc[bq+2] = fmaf(wxc[k4*4+u], v2[u], acc[bq+2]);
                    acc[bq+3] = fmaf(wxc[k4*4+u], v3[u], acc[bq+3]);
                }
            }
        }
    }

    #pragma unroll
    for (int i = 0; i < 16; ++i)
        x_out[(size_t)(b0 + wv*16 + i)*64 + lane] = acc[i];
}

// ---------------------------------------------------------------------------
extern "C" void kernel_launch(void* const* d_in, const int* in_sizes, int n_in,
                              void* d_out, int out_size, void* d_ws, size_t ws_size,
                              hipStream_t stream)
{
    const float* y    = (const float*)d_in[0];
    const float* H    = (const float*)d_in[1];
    const float* x0   = (const float*)d_in[2];
    const float* h    = (const float*)d_in[3];
    const float* ss   = (const float*)d_in[4];
    const float* Wih  = (const float*)d_in[5];
    const float* Whh  = (const float*)d_in[6];
    const float* bih  = (const float*)d_in[7];
    const float* bhh  = (const float*)d_in[8];
    const float* wx   = (const float*)d_in[9];
    const float* bx   = (const float*)d_in[10];
    const int*   iters= (const int*)d_in[11];

    const int B = in_sizes[0] / 64;                 // 16384
    float* x_out = (float*)d_out;                   // B*64
    float* h_new = (float*)d_out + (size_t)B * 64;  // B*256

    float* zws   = (float*)d_ws;                    // B*64
    float* wt_ih = zws + (size_t)B * 64;            // 64*256
    float* wt_hh = wt_ih + 64*256;                  // 256*256
    float* wxt   = wt_hh + 256*256;                 // 256*64

    transpose_prep<<<384, 256, 0, stream>>>(Wih, Whh, wx, wt_ih, wt_hh, wxt);
    solve_fused<<<B/PB, 256, 0, stream>>>(y, H, x0, ss, iters, zws);
    rnn_fused<<<B/BT, 256, 0, stream>>>(zws, h, wt_ih, wt_hh, bih, bhh, h_new);
    out_proj<<<B/CB, 256, 0, stream>>>(h_new, wxt, bx, x_out);
}

// Round 8
// 203.344 us; speedup vs baseline: 1.2799x; 1.2799x over previous
//
#include <hip/hip_runtime.h>

typedef short sh8  __attribute__((ext_vector_type(8)));   // 8 bf16 bit-patterns
typedef __bf16 bfv8 __attribute__((ext_vector_type(8)));
typedef float  fv4  __attribute__((ext_vector_type(4)));

__device__ __forceinline__ unsigned short f2bf(float x) {  // fp32 -> bf16 RNE
    unsigned u = __float_as_uint(x);
    return (unsigned short)((u + 0x7FFFu + ((u >> 16) & 1u)) >> 16);
}
__device__ __forceinline__ float bf2f(unsigned short b) {
    return __uint_as_float(((unsigned)b) << 16);
}
__device__ __forceinline__ fv4 mfma16(sh8 a, sh8 b, fv4 c) {
    return __builtin_amdgcn_mfma_f32_16x16x32_bf16(
        __builtin_bit_cast(bfv8, a), __builtin_bit_cast(bfv8, b), c, 0, 0, 0);
}

// ---------------------------------------------------------------------------
// Stage 1: per batch, G = HtH via bf16x2 MFMA, then 20 GD iters.
// Spill fix (r5/r7 lesson): acc (64 AGPR) and gcol (64 VGPR) must never be
// live together. Full G is stored to LDS in MFMA-output layout (stride 68
// pad: 16B-aligned rows, ~2-way store banks), acc dies, THEN gcol = row
// `lane` is loaded contiguously. G symmetric -> row lane == column lane.
// GD loop: x broadcast via wave-uniform ds_read_b128 (HW broadcast, DS pipe),
// VALU does pure fma. No readlane in hot paths (r2/r6: VALU<->SGPR
// wait-states ran at ~2.4x nominal issue cost).
// LDS 17.4 KB/wave: bf16 hi/lo staging planes (8 KB) overlaid by G (17 KB).
// 128-thread blocks = 2 waves, 1 batch each, no __syncthreads needed.
// ---------------------------------------------------------------------------
#define PB  2
#define GS  68

__global__ __launch_bounds__(128, 2) void solve_fused(
    const float* __restrict__ y, const float* __restrict__ H,
    const float* __restrict__ x0, const float* __restrict__ step_size,
    const int* __restrict__ iters, float* __restrict__ z_out)
{
    __shared__ __align__(16) float gshared[PB * 64 * GS];   // 2 x 17408 B
    __shared__ __align__(16) float xbuf[PB * 64];
    const int lane = threadIdx.x & 63;
    const int wv   = threadIdx.x >> 6;
    const int b    = blockIdx.x * PB + wv;

    float* gm  = gshared + wv * 64 * GS;          // [64][GS] fp32 G
    short* hip = (short*)gm;                      // [64][32] hi plane (4 KB)
    short* lop = hip + 2048;                      // [64][32] lo plane (4 KB)
    float* xb_ = xbuf + wv * 64;

    const float* __restrict__ Hb = H + (size_t)b * 4096;
    xb_[lane] = y[(size_t)b * 64 + lane];         // y -> broadcast buffer
    const int fr = lane & 15, fg = lane >> 4;

    fv4 acc[4][4];
    #pragma unroll
    for (int mt = 0; mt < 4; ++mt)
        #pragma unroll
        for (int nt = 0; nt < 4; ++nt)
            acc[mt][nt] = fv4{0.f, 0.f, 0.f, 0.f};

    float hty0 = 0.f, hty1 = 0.f, hty2 = 0.f, hty3 = 0.f;

    #pragma unroll
    for (int kk = 0; kk < 2; ++kk) {
        // --- stream-stage 32 rows of H (k-half kk): load, Hty-fma, cvt, write
        #pragma unroll
        for (int g = 0; g < 4; ++g) {
            const int r0 = kk * 32 + g * 8;
            float hv[8];
            #pragma unroll
            for (int i = 0; i < 8; ++i)
                hv[i] = Hb[(size_t)(r0 + i) * 64 + lane];

            // y[r0..r0+7] via uniform LDS reads (broadcast, DS pipe)
            const fv4 ya = *(const fv4*)(xb_ + r0);
            const fv4 yb = *(const fv4*)(xb_ + r0 + 4);
            hty0 = fmaf(hv[0], ya[0], hty0);
            hty1 = fmaf(hv[1], ya[1], hty1);
            hty2 = fmaf(hv[2], ya[2], hty2);
            hty3 = fmaf(hv[3], ya[3], hty3);
            hty0 = fmaf(hv[4], yb[0], hty0);
            hty1 = fmaf(hv[5], yb[1], hty1);
            hty2 = fmaf(hv[6], yb[2], hty2);
            hty3 = fmaf(hv[7], yb[3], hty3);

            sh8 vhi, vlo;
            #pragma unroll
            for (int i = 0; i < 8; ++i) {
                const unsigned short hbf = f2bf(hv[i]);
                vhi[i] = (short)hbf;
                vlo[i] = (short)f2bf(hv[i] - bf2f(hbf));
            }
            // chunk swizzle: chunk g of row `lane` stored at chunk g^(lane&3)
            const int sw = (g ^ (lane & 3)) * 8;
            *(sh8*)(hip + lane * 32 + sw) = vhi;
            *(sh8*)(lop + lane * 32 + sw) = vlo;
        }

        // --- fragments for this k-half: row = 16tt+fr, k-chunk fg (swizzled)
        sh8 fh[4], fl[4];
        #pragma unroll
        for (int tt = 0; tt < 4; ++tt) {
            const int row = tt * 16 + fr;
            const int sw  = (fg ^ (row & 3)) * 8;
            fh[tt] = *(const sh8*)(hip + row * 32 + sw);
            fl[tt] = *(const sh8*)(lop + row * 32 + sw);
        }

        // --- 48 MFMAs: hi*hi + hi*lo + lo*hi, fp32 accumulate
        #pragma unroll
        for (int mt = 0; mt < 4; ++mt)
            #pragma unroll
            for (int nt = 0; nt < 4; ++nt) {
                fv4 a = acc[mt][nt];
                a = mfma16(fh[mt], fh[nt], a);
                a = mfma16(fh[mt], fl[nt], a);
                a = mfma16(fl[mt], fh[nt], a);
                acc[mt][nt] = a;
            }

        // fragment reads must land before the planes are overwritten
        asm volatile("s_waitcnt lgkmcnt(0)" ::: "memory");
    }

    const float hty = (hty0 + hty1) + (hty2 + hty3);

    // --- full G store in MFMA D layout (m89: col=lane&15, row=(lane>>4)*4+i)
    // Planes are dead (lgkmcnt(0) above). Store banks ~2-way (free).
    #pragma unroll
    for (int mt = 0; mt < 4; ++mt)
        #pragma unroll
        for (int nt = 0; nt < 4; ++nt)
            #pragma unroll
            for (int i = 0; i < 4; ++i)
                gm[(mt * 16 + fg * 4 + i) * GS + nt * 16 + fr] = acc[mt][nt][i];

    // acc is now dead -> gcol can take clean registers (no overlap, no spill).
    // Same-wave DS ops are in-order; asm barrier stops compiler reordering.
    asm volatile("" ::: "memory");

    float gcol[64];                               // = G row lane (symmetric)
    #pragma unroll
    for (int s4 = 0; s4 < 16; ++s4) {
        const fv4 g4 = *(const fv4*)(gm + lane * GS + s4 * 4);
        gcol[s4*4+0] = g4[0]; gcol[s4*4+1] = g4[1];
        gcol[s4*4+2] = g4[2]; gcol[s4*4+3] = g4[3];
    }

    // --- GD loop: x broadcast via uniform ds_read_b128 (no readlane).
    float xv = x0[(size_t)b * 64 + lane];
    const float ts = 2.0f * step_size[0];
    const int n_it = iters[0];

    for (int it = 0; it < n_it; ++it) {
        xb_[lane] = xv;
        float w0=0.f,w1=0.f,w2=0.f,w3=0.f,w4=0.f,w5=0.f,w6=0.f,w7=0.f;
        #pragma unroll
        for (int p = 0; p < 8; ++p) {
            const fv4 xa = *(const fv4*)(xb_ + p * 8);       // uniform -> bcast
            const fv4 xc = *(const fv4*)(xb_ + p * 8 + 4);
            w0 = fmaf(gcol[p*8+0], xa[0], w0);
            w1 = fmaf(gcol[p*8+1], xa[1], w1);
            w2 = fmaf(gcol[p*8+2], xa[2], w2);
            w3 = fmaf(gcol[p*8+3], xa[3], w3);
            w4 = fmaf(gcol[p*8+4], xc[0], w4);
            w5 = fmaf(gcol[p*8+5], xc[1], w5);
            w6 = fmaf(gcol[p*8+6], xc[2], w6);
            w7 = fmaf(gcol[p*8+7], xc[3], w7);
        }
        const float w = ((w0+w1)+(w2+w3)) + ((w4+w5)+(w6+w7));
        xv = fmaf(ts, hty - w, xv);
    }

    z_out[(size_t)b * 64 + lane] = xv;
}

// ---------------------------------------------------------------------------
// Weight transposes so per-feature weight loads coalesce (runs once, tiny).
// ---------------------------------------------------------------------------
__global__ __launch_bounds__(256) void transpose_prep(
    const float* __restrict__ Wih, const float* __restrict__ Whh,
    const float* __restrict__ wx, float* __restrict__ wt_ih,
    float* __restrict__ wt_hh, float* __restrict__ wxt)
{
    int idx = blockIdx.x*256 + threadIdx.x;
    if (idx < 64*256) {
        int k = idx >> 8, j = idx & 255;
        wt_ih[idx] = Wih[j*64 + k];
        return;
    }
    idx -= 64*256;
    if (idx < 256*256) {
        int k = idx >> 8, j = idx & 255;
        wt_hh[idx] = Whh[j*256 + k];
        return;
    }
    idx -= 256*256;
    {
        int k = idx >> 6, u = idx & 63;
        wxt[idx] = wx[u*256 + k];
    }
}

// ---------------------------------------------------------------------------
// Stage 2: h_new[b][j] = relu(z[b]·W_ih[j] + h[b]·W_hh[j] + b_ih[j] + b_hh[j])
// ---------------------------------------------------------------------------
#define BT   32
#define ASTR 324

__global__ __launch_bounds__(256) void rnn_fused(
    const float* __restrict__ z, const float* __restrict__ h,
    const float* __restrict__ wt_ih, const float* __restrict__ wt_hh,
    const float* __restrict__ b_ih, const float* __restrict__ b_hh,
    float* __restrict__ h_new)
{
    __shared__ __align__(16) float act[BT*ASTR];   // 41472 B
    const int t = threadIdx.x;
    const int b0 = blockIdx.x * BT;

    #pragma unroll
    for (int i = 0; i < 2; ++i) {          // z tile: 32 x 64
        int f = t + 256*i, b = f >> 4, c = (f & 15) * 4;
        *(fv4*)(act + b*ASTR + c) = *(const fv4*)(z + (size_t)(b0+b)*64 + c);
    }
    #pragma unroll
    for (int i = 0; i < 8; ++i) {          // h tile: 32 x 256
        int f = t + 256*i, b = f >> 6, c = (f & 63) * 4;
        *(fv4*)(act + b*ASTR + 64 + c) = *(const fv4*)(h + (size_t)(b0+b)*256 + c);
    }
    __syncthreads();

    float acc[BT];
    {
        const float bias = b_ih[t] + b_hh[t];
        #pragma unroll
        for (int b = 0; b < BT; ++b) acc[b] = bias;
    }

    float w[64];
    #pragma unroll 1
    for (int kc = 0; kc < 5; ++kc) {       // k-chunks: 0 -> z, 1..4 -> h
        if (kc == 0) {
            #pragma unroll
            for (int k = 0; k < 64; ++k) w[k] = wt_ih[k*256 + t];
        } else {
            const float* wsrc = wt_hh + (size_t)(kc-1)*64*256;
            #pragma unroll
            for (int k = 0; k < 64; ++k) w[k] = wsrc[k*256 + t];
        }
        const int abase = kc*64;
        #pragma unroll
        for (int bq = 0; bq < BT; bq += 4) {
            const float* a0 = act + (bq+0)*ASTR + abase;
            const float* a1 = act + (bq+1)*ASTR + abase;
            const float* a2 = act + (bq+2)*ASTR + abase;
            const float* a3 = act + (bq+3)*ASTR + abase;
            #pragma unroll
            for (int k4 = 0; k4 < 16; ++k4) {
                fv4 v0 = *(const fv4*)(a0 + k4*4);
                fv4 v1 = *(const fv4*)(a1 + k4*4);
                fv4 v2 = *(const fv4*)(a2 + k4*4);
                fv4 v3 = *(const fv4*)(a3 + k4*4);
                #pragma unroll
                for (int u = 0; u < 4; ++u) {
                    acc[bq+0] = fmaf(w[k4*4+u], v0[u], acc[bq+0]);
                    acc[bq+1] = fmaf(w[k4*4+u], v1[u], acc[bq+1]);
                    acc[bq+2] = fmaf(w[k4*4+u], v2[u], acc[bq+2]);
                    acc[bq+3] = fmaf(w[k4*4+u], v3[u], acc[bq+3]);
                }
            }
        }
    }

    #pragma unroll
    for (int b = 0; b < BT; ++b)
        h_new[(size_t)(b0+b)*256 + t] = fmaxf(acc[b], 0.f);
}

// ---------------------------------------------------------------------------
// Stage 3: x_out[b][u] = h_new[b]·w_x[u] + b_x[u]
// ---------------------------------------------------------------------------
#define CB 64

__global__ __launch_bounds__(256) void out_proj(
    const float* __restrict__ h_new, const float* __restrict__ wxt,
    const float* __restrict__ b_x, float* __restrict__ x_out)
{
    __shared__ __align__(16) float hl[CB*256];   // 65536 B
    const int t = threadIdx.x, lane = t & 63, wv = t >> 6;
    const int b0 = blockIdx.x * CB;

    #pragma unroll
    for (int i = 0; i < 16; ++i) {
        int f = t + 256*i, b = f >> 6, c = (f & 63) * 4;
        *(fv4*)(hl + b*256 + c) = *(const fv4*)(h_new + (size_t)(b0+b)*256 + c);
    }
    __syncthreads();

    float acc[16];
    {
        const float bx = b_x[lane];
        #pragma unroll
        for (int i = 0; i < 16; ++i) acc[i] = bx;
    }

    float wxc[64];
    #pragma unroll 1
    for (int kc = 0; kc < 4; ++kc) {
        #pragma unroll
        for (int k = 0; k < 64; ++k)
            wxc[k] = wxt[(size_t)(kc*64 + k)*64 + lane];
        const int bb = wv * 16;
        #pragma unroll
        for (int bq = 0; bq < 16; bq += 4) {
            const float* h0 = hl + (bb+bq+0)*256 + kc*64;
            const float* h1 = hl + (bb+bq+1)*256 + kc*64;
            const float* h2 = hl + (bb+bq+2)*256 + kc*64;
            const float* h3 = hl + (bb+bq+3)*256 + kc*64;
            #pragma unroll
            for (int k4 = 0; k4 < 16; ++k4) {
                fv4 v0 = *(const fv4*)(h0 + k4*4);
                fv4 v1 = *(const fv4*)(h1 + k4*4);
                fv4 v2 = *(const fv4*)(h2 + k4*4);
                fv4 v3 = *(const fv4*)(h3 + k4*4);
                #pragma unroll
                for (int u = 0; u < 4; ++u) {
                    acc[bq+0] = fmaf(wxc[k4*4+u], v0[u], acc[bq+0]);
                    acc[bq+1] = fmaf(wxc[k4*4+u], v1[u], acc[bq+1]);
                    acc[bq+2] = fmaf(wxc[k4*4+u], v2[u], acc[bq+2]);
                    acc[bq+3] = fmaf(wxc[k4*4+u], v3[u], acc[bq+3]);
                }
            }
        }
    }

    #pragma unroll
    for (int i = 0; i < 16; ++i)
        x_out[(size_t)(b0 + wv*16 + i)*64 + lane] = acc[i];
}

// ---------------------------------------------------------------------------
extern "C" void kernel_launch(void* const* d_in, const int* in_sizes, int n_in,
                              void* d_out, int out_size, void* d_ws, size_t ws_size,
                              hipStream_t stream)
{
    const float* y    = (const float*)d_in[0];
    const float* H    = (const float*)d_in[1];
    const float* x0   = (const float*)d_in[2];
    const float* h    = (const float*)d_in[3];
    const float* ss   = (const float*)d_in[4];
    const float* Wih  = (const float*)d_in[5];
    const float* Whh  = (const float*)d_in[6];
    const float* bih  = (const float*)d_in[7];
    const float* bhh  = (const float*)d_in[8];
    const float* wx   = (const float*)d_in[9];
    const float* bx   = (const float*)d_in[10];
    const int*   iters= (const int*)d_in[11];

    const int B = in_sizes[0] / 64;                 // 16384
    float* x_out = (float*)d_out;                   // B*64
    float* h_new = (float*)d_out + (size_t)B * 64;  // B*256

    float* zws   = (float*)d_ws;                    // B*64
    float* wt_ih = zws + (size_t)B * 64;            // 64*256
    float* wt_hh = wt_ih + 64*256;                  // 256*256
    float* wxt   = wt_hh + 256*256;                 // 256*64

    transpose_prep<<<384, 256, 0, stream>>>(Wih, Whh, wx, wt_ih, wt_hh, wxt);
    solve_fused<<<B/PB, 128, 0, stream>>>(y, H, x0, ss, iters, zws);
    rnn_fused<<<B/BT, 256, 0, stream>>>(zws, h, wt_ih, wt_hh, bih, bhh, h_new);
    out_proj<<<B/CB, 256, 0, stream>>>(h_new, wxt, bx, x_out);
}